// Round 7
// baseline (297.678 us; speedup 1.0000x reference)
//
#include <hip/hip_runtime.h>

// AdaptiveSpectrumLayer: B=128, H=T=512, F=16, HID=64, NF=257
// v6: DFTs as MFMA GEMMs against pre-swizzled bf16 twiddle tables.
// k_fftg: rfft (+csd add). k_csdg: csd = TW x autocorr. k_recong: irfft with
// blend-in-staging and LayerNorm epilogue (16-lane shfl reduce).
// k_gemm / k_new / k_wred / k_wgt unchanged from v5 (proven).

#define NF_ 257
#define KDIM 16448   // NF_*64
#define SPK 16
#define SORTHO 0.04419417382f   // 1/sqrt(512)

typedef __attribute__((ext_vector_type(8))) short short8;
typedef __attribute__((ext_vector_type(4))) float floatx4;

__device__ __forceinline__ unsigned int f2bf(float x) {
  union { float f; unsigned int u; } v; v.f = x;
  return (v.u + 0x7FFFu + ((v.u >> 16) & 1u)) >> 16;
}
__device__ __forceinline__ float bf2f(unsigned int u16) {
  union { unsigned int u; float f; } v; v.u = u16 << 16;
  return v.f;
}

// ---------- K0: W_gate (16448 x 257 f32) -> wgt bf16 transposed (320 x 16448)
__global__ __launch_bounds__(256) void k_wgt(const float* __restrict__ Wg,
                                             unsigned short* __restrict__ wgt) {
  __shared__ float tile[64][33];
  const int tid = threadIdx.x;
  const int k0 = blockIdx.x * 64, n0 = blockIdx.y * 32;
  const int c = tid & 31, r8 = tid >> 5;
  const int n = n0 + c;
#pragma unroll
  for (int j = 0; j < 8; ++j) {
    int rr = r8 + j * 8;
    tile[rr][c] = (n < NF_) ? Wg[(k0 + rr) * NF_ + n] : 0.f;
  }
  __syncthreads();
  const int c64 = tid & 63, n4 = tid >> 6;
#pragma unroll
  for (int j = 0; j < 8; ++j) {
    int nn = n4 + j * 4;
    wgt[(n0 + nn) * KDIM + k0 + c64] = (unsigned short)f2bf(tile[c64][nn]);
  }
}

// ---------- K1a: rfft twiddle table, fragment-major, S folded.
// TWf[tile(34)][ks(16)][quad][l15][8j]; row grow=tile*16+l15: 2k=cos,2k+1=-sin.
__global__ __launch_bounds__(256) void k_tw(unsigned short* __restrict__ TWf) {
  const int slot = blockIdx.x * 256 + threadIdx.x;   // < 34816
  const int tile = slot >> 10, rem = slot & 1023;
  const int ks = rem >> 6, quad = (rem >> 4) & 3, l15 = rem & 15;
  const int grow = tile * 16 + l15;
  unsigned int pk[4];
#pragma unroll
  for (int jp = 0; jp < 4; ++jp) {
    float v0 = 0.f, v1 = 0.f;
    if (grow < 514) {
      const int k = grow >> 1;
      const int t0 = ks * 32 + quad * 8 + jp * 2;
      float s0, c0, s1, c1;
      __sincosf((float)((k * t0) & 511) * 0.01227184630f, &s0, &c0);
      __sincosf((float)((k * (t0 + 1)) & 511) * 0.01227184630f, &s1, &c1);
      v0 = (grow & 1) ? -s0 * SORTHO : c0 * SORTHO;
      v1 = (grow & 1) ? -s1 * SORTHO : c1 * SORTHO;
    }
    pk[jp] = f2bf(v0) | (f2bf(v1) << 16);
  }
  *(uint4*)(TWf + slot * 8) = make_uint4(pk[0], pk[1], pk[2], pk[3]);
}

// ---------- K1b: irfft twiddle table, fragment-major, S and Hermitian hw folded.
// ITWf[tile(32)][ks(17)][quad][l15][8j]; m=t=tile*16+l15, k-dim=2k+ri (544 pad).
__global__ __launch_bounds__(256) void k_itw(unsigned short* __restrict__ ITWf) {
  const int slot = blockIdx.x * 256 + threadIdx.x;   // < 34816
  const int tile = slot / 1088, rem = slot % 1088;
  const int ks = rem >> 6, sub = rem & 63;
  const int quad = sub >> 4, l15 = sub & 15;
  const int t = tile * 16 + l15;
  unsigned int pk[4];
#pragma unroll
  for (int jp = 0; jp < 4; ++jp) {
    float v0 = 0.f, v1 = 0.f;
#pragma unroll
    for (int h = 0; h < 2; ++h) {
      const int kidx = ks * 32 + quad * 8 + jp * 2 + h;
      float v = 0.f;
      if (kidx < 514) {
        const int k = kidx >> 1;
        const float hw = (k == 0 || k == 256) ? SORTHO : 2.f * SORTHO;
        float s, c;
        __sincosf((float)((k * t) & 511) * 0.01227184630f, &s, &c);
        v = (kidx & 1) ? -s * hw : c * hw;
      }
      if (h == 0) v0 = v; else v1 = v;
    }
    pk[jp] = f2bf(v0) | (f2bf(v1) << 16);
  }
  *(uint4*)(ITWf + slot * 8) = make_uint4(pk[0], pk[1], pk[2], pk[3]);
}

// ---------- K2: autocorr half-lags of the row-sum. acm[b][0..256].
__global__ __launch_bounds__(256) void k_acor(const float* __restrict__ x,
                                              float* __restrict__ acm) {
  __shared__ float sl[768];
  __shared__ float red[4];
  const int tid = threadIdx.x, bb = blockIdx.x;
  for (int t = tid; t < 768; t += 256) {
    float v = 0.f;
    if (t < 512) {
      const float4* xp = (const float4*)(x + (bb * 512 + t) * 16);
      float4 a = xp[0], b = xp[1], c = xp[2], d = xp[3];
      v = a.x + a.y + a.z + a.w + b.x + b.y + b.z + b.w +
          c.x + c.y + c.z + c.w + d.x + d.y + d.z + d.w;
    }
    sl[t] = v;
  }
  __syncthreads();
  float a0 = 0.f, a1 = 0.f, a2 = 0.f, a3 = 0.f;
  for (int tau = 0; tau < 512; tau += 4) {
    float4 u = *(const float4*)&sl[tau];
    a0 = fmaf(u.x, sl[tau + tid], a0);
    a1 = fmaf(u.y, sl[tau + tid + 1], a1);
    a2 = fmaf(u.z, sl[tau + tid + 2], a2);
    a3 = fmaf(u.w, sl[tau + tid + 3], a3);
  }
  acm[bb * NF_ + tid] = (a0 + a1) + (a2 + a3);
  float p = sl[tid] * sl[tid + 256];
#pragma unroll
  for (int off = 32; off; off >>= 1) p += __shfl_down(p, off);
  if ((tid & 63) == 0) red[tid >> 6] = p;
  __syncthreads();
  if (tid == 0) acm[bb * NF_ + 256] = red[0] + red[1] + red[2] + red[3];
}

// ---------- K3: csd GEMM: csd[b][k]{re,im} = (TWf x OL^T)/256. 8 blocks.
__global__ __launch_bounds__(256) void k_csdg(const float* __restrict__ acm,
                                              const unsigned short* __restrict__ TWf,
                                              float* __restrict__ csd) {
  __shared__ __align__(16) unsigned short Bs[16 * 512];
  const int tid = threadIdx.x, b0 = blockIdx.x * 16;
  for (int it = 0; it < 32; ++it) {
    int e = it * 256 + tid;
    int j = e >> 9, t = e & 511;
    int d = t - 255;
    float val = acm[(b0 + j) * NF_ + (d < 0 ? -d : d)];
    Bs[j * 512 + (((t >> 3) ^ (j & 7)) * 8) + (t & 7)] = (unsigned short)f2bf(val);
  }
  __syncthreads();
  const int lane = tid & 63, wave = tid >> 6;
  const int l15 = lane & 15, quad = lane >> 4;
  const int nt = (37 - wave) >> 2;          // 9,9,8,8
  floatx4 acc[9];
#pragma unroll
  for (int i = 0; i < 9; ++i) acc[i] = (floatx4){0.f, 0.f, 0.f, 0.f};
  for (int ks = 0; ks < 16; ++ks) {
    const int c = ks * 4 + quad;
    short8 bf = *(const short8*)&Bs[l15 * 512 + ((c ^ (l15 & 7)) * 8)];
    for (int i = 0; i < nt; ++i) {
      const int g = wave + 4 * i;
      short8 af = *(const short8*)(TWf + g * 8192 + ks * 512 + quad * 128 + l15 * 8);
      acc[i] = __builtin_amdgcn_mfma_f32_16x16x32_bf16(af, bf, acc[i], 0, 0, 0);
    }
  }
  for (int i = 0; i < nt; ++i) {
    const int g = wave + 4 * i;
#pragma unroll
    for (int r = 0; r < 4; ++r) {
      const int grow = g * 16 + quad * 4 + r;
      if (grow < 514) {
        const int k = grow >> 1, ri = grow & 1;
        csd[((b0 + l15) * NF_ + k) * 2 + ri] = acc[i][r] * 0.00390625f;
      }
    }
  }
}

// ---------- K4: rfft GEMM: fftc[b][k][f]{re,im} = TWf x X^T + csd. grid (2,128).
__global__ __launch_bounds__(256) void k_fftg(const float* __restrict__ x,
                                              const unsigned short* __restrict__ TWf,
                                              const float* __restrict__ csd,
                                              float* __restrict__ fftc) {
  __shared__ __align__(16) unsigned short Xs[16 * 512];
  const int tid = threadIdx.x, mh = blockIdx.x, bb = blockIdx.y;
  for (int it = 0; it < 32; ++it) {
    int e = it * 256 + tid;
    int f = e & 15, t = e >> 4;
    float val = x[(bb * 512 + t) * 16 + f];
    Xs[f * 512 + (((t >> 3) ^ (f & 7)) * 8) + (t & 7)] = (unsigned short)f2bf(val);
  }
  __syncthreads();
  const int lane = tid & 63, wave = tid >> 6;
  const int l15 = lane & 15, quad = lane >> 4;
  const int nt = (20 - wave) >> 2;          // 5,4,4,4
  floatx4 acc[5];
#pragma unroll
  for (int i = 0; i < 5; ++i) acc[i] = (floatx4){0.f, 0.f, 0.f, 0.f};
  for (int ks = 0; ks < 16; ++ks) {
    const int c = ks * 4 + quad;
    short8 bf = *(const short8*)&Xs[l15 * 512 + ((c ^ (l15 & 7)) * 8)];
    for (int i = 0; i < nt; ++i) {
      const int g = mh * 17 + wave + 4 * i;
      short8 af = *(const short8*)(TWf + g * 8192 + ks * 512 + quad * 128 + l15 * 8);
      acc[i] = __builtin_amdgcn_mfma_f32_16x16x32_bf16(af, bf, acc[i], 0, 0, 0);
    }
  }
  for (int i = 0; i < nt; ++i) {
    const int g = mh * 17 + wave + 4 * i;
#pragma unroll
    for (int r = 0; r < 4; ++r) {
      const int grow = g * 16 + quad * 4 + r;
      if (grow < 514) {
        const int k = grow >> 1, ri = grow & 1;
        fftc[((bb * NF_ + k) * 16 + l15) * 2 + ri] =
            acc[i][r] + csd[(bb * NF_ + k) * 2 + ri];
      }
    }
  }
}

// ---------- K5: new_fft[b][n][f] from recomputed proj + per-freq complexifier
__global__ __launch_bounds__(256) void k_new(const float* __restrict__ fftc,
                                             const float* __restrict__ W_proj,
                                             const float* __restrict__ b_proj,
                                             const float* __restrict__ mag_w,
                                             const float* __restrict__ mag_b,
                                             const float* __restrict__ phase_w,
                                             const float* __restrict__ phase_b,
                                             float* __restrict__ nf) {
  __shared__ float wp[256], bp[64];
  const int tid = threadIdx.x;
  wp[tid] = W_proj[tid];
  if (tid < 64) bp[tid] = b_proj[tid];
  __syncthreads();
  const int idx = blockIdx.x * 256 + tid;
  const int bn = idx >> 4;
  const int n = bn % NF_;
  float2 z = *(const float2*)(fftc + idx * 2);
  float d = z.x * z.x + z.y * z.y;
  float ir = d > 0.f ? rsqrtf(d) : 0.f;
  float mag = d * ir;
  float sn = z.y * ir;
  float cs = d > 0.f ? z.x * ir : 1.f;
  float fr = (float)n * 0.1953125f;  // 100/512
  float am = 0.f, ap = 0.f;
#pragma unroll 8
  for (int h = 0; h < 64; ++h) {
    float p = fmaf(mag, wp[h], fmaf(sn, wp[64 + h], fmaf(cs, wp[128 + h],
              fmaf(fr, wp[192 + h], bp[h]))));
    p = fmaxf(p, 0.f);
    am = fmaf(p, mag_w[n * 64 + h], am);
    ap = fmaf(p, phase_w[n * 64 + h], ap);
  }
  float m = fmaxf(am + mag_b[n], 0.f);
  float ph = 6.28318530718f / (1.f + __expf(-(ap + phase_b[n])));
  float sp, cp;
  __sincosf(ph, &sp, &cp);
  *(float2*)(nf + idx * 2) = make_float2(m * cp, m * sp);
}

// ---------- K6: gate GEMM (v5, unchanged). XOR-swizzled LDS, SPK=16.
__global__ __launch_bounds__(256, 2) void k_gemm(const float* __restrict__ fftc,
                                                 const float* __restrict__ W_proj,
                                                 const float* __restrict__ b_proj,
                                                 const unsigned short* __restrict__ wgt,
                                                 unsigned short* __restrict__ gpart) {
  __shared__ __align__(16) unsigned short As[128 * 64];
  __shared__ __align__(16) unsigned short Bs[160 * 64];
  __shared__ unsigned int zsp[128 * 17];
  const int tid = threadIdx.x;
  const int bid = blockIdx.x;
  const int xcd = bid & 7, jb = bid >> 3;
  const int mt = jb & 15;
  const int slice = xcd * 4 + (jb >> 4);
  const int sp = slice >> 1, nh = slice & 1;
  const int i0 = (NF_ * sp) >> 4, i1 = (NF_ * (sp + 1)) >> 4;
  const int ni = i1 - i0;

  const int r8 = tid >> 3, hg = tid & 7;
  float w0[8], w1[8], w2[8], w3[8], bpv[8];
#pragma unroll
  for (int jj = 0; jj < 8; ++jj) {
    int h = hg * 8 + jj;
    w0[jj] = W_proj[h];       w1[jj] = W_proj[64 + h];
    w2[jj] = W_proj[128 + h]; w3[jj] = W_proj[192 + h];
    bpv[jj] = b_proj[h];
  }
  const int nb2 = tid >> 3, kq = tid & 7;
  const unsigned short* bbase = wgt + (nh * 160 + nb2) * KDIM + kq * 8;

  const int lane = tid & 63, wave = tid >> 6;
  const int wm = wave & 1, wn = wave >> 1;
  const int l15 = lane & 15, quad = lane >> 4;

  floatx4 acc[4][5];
#pragma unroll
  for (int a = 0; a < 4; ++a)
#pragma unroll
    for (int b = 0; b < 5; ++b) acc[a][b] = (floatx4){0.f, 0.f, 0.f, 0.f};

  uint4 bv[5];
#pragma unroll
  for (int q = 0; q < 5; ++q)
    bv[q] = *(const uint4*)(bbase + q * (32 * KDIM) + i0 * 64);
  for (int li = tid; li < 128 * ni; li += 256) {
    int r = li & 127, ii = li >> 7;
    int gm = mt * 128 + r;
    float2 z = *(const float2*)(fftc + (((gm >> 4) * NF_ + i0 + ii) * 16 + (gm & 15)) * 2);
    zsp[r * 17 + ii] = f2bf(z.x) | (f2bf(z.y) << 16);
  }
  __syncthreads();

  for (int i = i0; i < i1; ++i) {
    const int ii = i - i0;
    const float fr = (float)i * 0.1953125f;
    unsigned int pk[4][4];
#pragma unroll
    for (int g = 0; g < 4; ++g) {
      unsigned int zp = zsp[(r8 + 32 * g) * 17 + ii];
      float zr = bf2f(zp & 0xFFFFu), zi = bf2f(zp >> 16);
      float d = zr * zr + zi * zi;
      float ir = d > 0.f ? rsqrtf(d) : 0.f;
      float mag = d * ir, sn = zi * ir, cs = d > 0.f ? zr * ir : 1.f;
#pragma unroll
      for (int jj = 0; jj < 4; ++jj) {
        float p0 = fmaf(mag, w0[2 * jj], fmaf(sn, w1[2 * jj],
                   fmaf(cs, w2[2 * jj], fmaf(fr, w3[2 * jj], bpv[2 * jj]))));
        float p1 = fmaf(mag, w0[2 * jj + 1], fmaf(sn, w1[2 * jj + 1],
                   fmaf(cs, w2[2 * jj + 1], fmaf(fr, w3[2 * jj + 1], bpv[2 * jj + 1]))));
        p0 = fmaxf(p0, 0.f); p1 = fmaxf(p1, 0.f);
        pk[g][jj] = f2bf(p0) | (f2bf(p1) << 16);
      }
    }
    __syncthreads();
#pragma unroll
    for (int g = 0; g < 4; ++g) {
      int row = r8 + 32 * g;
      *(uint4*)&As[row * 64 + ((hg ^ (row & 7)) * 8)] =
          make_uint4(pk[g][0], pk[g][1], pk[g][2], pk[g][3]);
    }
#pragma unroll
    for (int q = 0; q < 5; ++q) {
      int row = nb2 + 32 * q;
      *(uint4*)&Bs[row * 64 + ((kq ^ (row & 7)) * 8)] = bv[q];
    }
    __syncthreads();
    {
      const int ix = (i + 1 < i1) ? i + 1 : i;
#pragma unroll
      for (int q = 0; q < 5; ++q)
        bv[q] = *(const uint4*)(bbase + q * (32 * KDIM) + ix * 64);
    }
#pragma unroll
    for (int kh = 0; kh < 2; ++kh) {
      const int kqr = kh * 4 + quad;
      short8 af[4];
#pragma unroll
      for (int mi = 0; mi < 4; ++mi) {
        int row = wm * 64 + mi * 16 + l15;
        af[mi] = *(const short8*)&As[row * 64 + ((kqr ^ (row & 7)) * 8)];
      }
#pragma unroll
      for (int nn = 0; nn < 5; ++nn) {
        int row = wn * 80 + nn * 16 + l15;
        short8 bfv = *(const short8*)&Bs[row * 64 + ((kqr ^ (row & 7)) * 8)];
#pragma unroll
        for (int mi = 0; mi < 4; ++mi)
          acc[mi][nn] = __builtin_amdgcn_mfma_f32_16x16x32_bf16(af[mi], bfv,
                                                                acc[mi][nn], 0, 0, 0);
      }
    }
  }
  unsigned short* gp = gpart + (size_t)slice * (2048 * 160);
#pragma unroll
  for (int mi = 0; mi < 4; ++mi)
#pragma unroll
    for (int nn = 0; nn < 5; ++nn)
#pragma unroll
      for (int r = 0; r < 4; ++r) {
        int row = mt * 128 + wm * 64 + mi * 16 + quad * 4 + r;
        int col = wn * 80 + nn * 16 + l15;
        gp[row * 160 + col] = (unsigned short)f2bf(acc[mi][nn][r]);
      }
}

// ---------- K6r: sum split-K bf16 partials + bias -> SiLU -> sigmoid -> w
__global__ __launch_bounds__(256) void k_wred(const unsigned short* __restrict__ gpart,
                                              const float* __restrict__ b_gate,
                                              float* __restrict__ wbuf) {
  const int m = blockIdx.x;
  for (int n = threadIdx.x; n < NF_; n += 256) {
    const int half = (n >= 160) ? 1 : 0;
    const int col = n - half * 160;
    float g = b_gate[n];
#pragma unroll
    for (int s2 = 0; s2 < SPK; ++s2)
      g += bf2f((unsigned int)gpart[((size_t)(s2 * 2 + half) * 2048 + m) * 160 + col]);
    float sg = 1.f / (1.f + __expf(-g));
    float gs = g * sg;
    wbuf[m * NF_ + n] = 1.f / (1.f + __expf(-gs));
  }
}

// ---------- K7: irfft GEMM: out = LN(ITWf x WF^T + x). grid (2,128).
__global__ __launch_bounds__(256) void k_recong(const float* __restrict__ fftc,
                                                const float* __restrict__ nfb,
                                                const float* __restrict__ wbuf,
                                                const unsigned short* __restrict__ ITWf,
                                                const float* __restrict__ x,
                                                const float* __restrict__ ln_g,
                                                const float* __restrict__ ln_b,
                                                float* __restrict__ out) {
  __shared__ __align__(16) unsigned short WFs[16 * 576];
  const int tid = threadIdx.x, th = blockIdx.x, bb = blockIdx.y;
  for (int it = 0; it < 34; ++it) {
    int e = it * 256 + tid;        // < 8704 = 16*544
    int f = e & 15, row = e >> 4;
    float val = 0.f;
    if (row < 514) {
      int k = row >> 1, ri = row & 1;
      int base = ((bb * NF_ + k) * 16 + f) * 2 + ri;
      float fz = fftc[base], nz = nfb[base];
      float wv = wbuf[(bb * 16 + f) * NF_ + k];
      val = fz + wv * (nz - fz);
    }
    WFs[f * 576 + (((row >> 3) ^ (f & 7)) * 8) + (row & 7)] = (unsigned short)f2bf(val);
  }
  __syncthreads();
  const int lane = tid & 63, wave = tid >> 6;
  const int l15 = lane & 15, quad = lane >> 4;
  const float gg = ln_g[l15], gb = ln_b[l15];
  floatx4 acc[4];
#pragma unroll
  for (int i = 0; i < 4; ++i) acc[i] = (floatx4){0.f, 0.f, 0.f, 0.f};
  for (int ks = 0; ks < 17; ++ks) {
    const int c = ks * 4 + quad;
    short8 bf = *(const short8*)&WFs[l15 * 576 + ((c ^ (l15 & 7)) * 8)];
#pragma unroll
    for (int i = 0; i < 4; ++i) {
      const int tg = th * 16 + wave + 4 * i;
      short8 af = *(const short8*)(ITWf + tg * 8704 + ks * 512 + quad * 128 + l15 * 8);
      acc[i] = __builtin_amdgcn_mfma_f32_16x16x32_bf16(af, bf, acc[i], 0, 0, 0);
    }
  }
#pragma unroll
  for (int i = 0; i < 4; ++i) {
    const int tg = th * 16 + wave + 4 * i;
#pragma unroll
    for (int r = 0; r < 4; ++r) {
      const int t = tg * 16 + quad * 4 + r;
      float y = acc[i][r] + x[(bb * 512 + t) * 16 + l15];
      float s1 = y, s2 = y * y;
#pragma unroll
      for (int m = 1; m < 16; m <<= 1) {
        s1 += __shfl_xor(s1, m);
        s2 += __shfl_xor(s2, m);
      }
      float mu = s1 * 0.0625f;
      float var = s2 * 0.0625f - mu * mu;
      float rs = rsqrtf(var + 1e-5f);
      out[(bb * 512 + t) * 16 + l15] = (y - mu) * rs * gg + gb;
    }
  }
}

extern "C" void kernel_launch(void* const* d_in, const int* in_sizes, int n_in,
                              void* d_out, int out_size, void* d_ws, size_t ws_size,
                              hipStream_t stream) {
  const float* x = (const float*)d_in[0];
  const float* W_proj = (const float*)d_in[1];
  const float* b_proj = (const float*)d_in[2];
  const float* W_gate = (const float*)d_in[3];
  const float* b_gate = (const float*)d_in[4];
  const float* mag_w = (const float*)d_in[5];
  const float* mag_b = (const float*)d_in[6];
  const float* phase_w = (const float*)d_in[7];
  const float* phase_b = (const float*)d_in[8];
  const float* ln_g = (const float*)d_in[9];
  const float* ln_b = (const float*)d_in[10];
  float* out = (float*)d_out;
  float* ws = (float*)d_ws;

  // workspace (float slots), ~43.5 MB total
  float* fftc = ws;                                          // 1,052,672
  float* nfb = ws + 1052672;                                 // 1,052,672
  float* wbuf = ws + 2105344;                                //   526,336
  float* csd = ws + 2631680;                                 //    65,792
  float* acm = ws + 2697472;                                 //    32,896
  unsigned short* gpart = (unsigned short*)(ws + 2730368);   // 32*2048*160
  unsigned short* wgt = (unsigned short*)(ws + 7973248);     // 320*16448
  unsigned short* TWf = (unsigned short*)(ws + 10604928);    // 278,528 sh
  unsigned short* ITWf = (unsigned short*)(ws + 10744192);   // 278,528 sh

  hipLaunchKernelGGL(k_wgt, dim3(257, 10), dim3(256), 0, stream, W_gate, wgt);
  hipLaunchKernelGGL(k_tw, dim3(136), dim3(256), 0, stream, TWf);
  hipLaunchKernelGGL(k_itw, dim3(136), dim3(256), 0, stream, ITWf);
  hipLaunchKernelGGL(k_acor, dim3(128), dim3(256), 0, stream, x, acm);
  hipLaunchKernelGGL(k_csdg, dim3(8), dim3(256), 0, stream, acm, TWf, csd);
  hipLaunchKernelGGL(k_fftg, dim3(2, 128), dim3(256), 0, stream, x, TWf, csd, fftc);
  hipLaunchKernelGGL(k_new, dim3(2056), dim3(256), 0, stream, fftc, W_proj, b_proj,
                     mag_w, mag_b, phase_w, phase_b, nfb);
  hipLaunchKernelGGL(k_gemm, dim3(512), dim3(256), 0, stream, fftc, W_proj,
                     b_proj, wgt, gpart);
  hipLaunchKernelGGL(k_wred, dim3(2048), dim3(256), 0, stream, gpart, b_gate, wbuf);
  hipLaunchKernelGGL(k_recong, dim3(2, 128), dim3(256), 0, stream, fftc, nfb, wbuf,
                     ITWf, x, ln_g, ln_b, out);
}

// Round 8
// 238.827 us; speedup vs baseline: 1.2464x; 1.2464x over previous
//
#include <hip/hip_runtime.h>

// AdaptiveSpectrumLayer: B=128, H=T=512, F=16, HID=64, NF=257
// v7: k_csd restored (fused autocorr+rotation DFT, v4-proven). k_gemm SPK=32,
// 3 blocks/CU. k_fftg/k_recong: 512 threads, batched TWf fragment loads,
// wbuf pre-staged to LDS (coalesced).

#define NF_ 257
#define KDIM 16448   // NF_*64
#define SPK 32
#define SORTHO 0.04419417382f   // 1/sqrt(512)

typedef __attribute__((ext_vector_type(8))) short short8;
typedef __attribute__((ext_vector_type(4))) float floatx4;

__device__ __forceinline__ unsigned int f2bf(float x) {
  union { float f; unsigned int u; } v; v.f = x;
  return (v.u + 0x7FFFu + ((v.u >> 16) & 1u)) >> 16;
}
__device__ __forceinline__ float bf2f(unsigned int u16) {
  union { unsigned int u; float f; } v; v.u = u16 << 16;
  return v.f;
}

// ---------- K0: W_gate (16448 x 257 f32) -> wgt bf16 transposed (320 x 16448)
__global__ __launch_bounds__(256) void k_wgt(const float* __restrict__ Wg,
                                             unsigned short* __restrict__ wgt) {
  __shared__ float tile[64][33];
  const int tid = threadIdx.x;
  const int k0 = blockIdx.x * 64, n0 = blockIdx.y * 32;
  const int c = tid & 31, r8 = tid >> 5;
  const int n = n0 + c;
#pragma unroll
  for (int j = 0; j < 8; ++j) {
    int rr = r8 + j * 8;
    tile[rr][c] = (n < NF_) ? Wg[(k0 + rr) * NF_ + n] : 0.f;
  }
  __syncthreads();
  const int c64 = tid & 63, n4 = tid >> 6;
#pragma unroll
  for (int j = 0; j < 8; ++j) {
    int nn = n4 + j * 4;
    wgt[(n0 + nn) * KDIM + k0 + c64] = (unsigned short)f2bf(tile[c64][nn]);
  }
}

// ---------- K1a: rfft twiddle table, fragment-major, S folded.
__global__ __launch_bounds__(256) void k_tw(unsigned short* __restrict__ TWf) {
  const int slot = blockIdx.x * 256 + threadIdx.x;   // < 34816
  const int tile = slot >> 10, rem = slot & 1023;
  const int ks = rem >> 6, quad = (rem >> 4) & 3, l15 = rem & 15;
  const int grow = tile * 16 + l15;
  unsigned int pk[4];
#pragma unroll
  for (int jp = 0; jp < 4; ++jp) {
    float v0 = 0.f, v1 = 0.f;
    if (grow < 514) {
      const int k = grow >> 1;
      const int t0 = ks * 32 + quad * 8 + jp * 2;
      float s0, c0, s1, c1;
      __sincosf((float)((k * t0) & 511) * 0.01227184630f, &s0, &c0);
      __sincosf((float)((k * (t0 + 1)) & 511) * 0.01227184630f, &s1, &c1);
      v0 = (grow & 1) ? -s0 * SORTHO : c0 * SORTHO;
      v1 = (grow & 1) ? -s1 * SORTHO : c1 * SORTHO;
    }
    pk[jp] = f2bf(v0) | (f2bf(v1) << 16);
  }
  *(uint4*)(TWf + slot * 8) = make_uint4(pk[0], pk[1], pk[2], pk[3]);
}

// ---------- K1b: irfft twiddle table, fragment-major, S + Hermitian folded.
__global__ __launch_bounds__(256) void k_itw(unsigned short* __restrict__ ITWf) {
  const int slot = blockIdx.x * 256 + threadIdx.x;   // < 34816
  const int tile = slot / 1088, rem = slot % 1088;
  const int ks = rem >> 6, sub = rem & 63;
  const int quad = sub >> 4, l15 = sub & 15;
  const int t = tile * 16 + l15;
  unsigned int pk[4];
#pragma unroll
  for (int jp = 0; jp < 4; ++jp) {
    float v0 = 0.f, v1 = 0.f;
#pragma unroll
    for (int h = 0; h < 2; ++h) {
      const int kidx = ks * 32 + quad * 8 + jp * 2 + h;
      float v = 0.f;
      if (kidx < 514) {
        const int k = kidx >> 1;
        const float hw = (k == 0 || k == 256) ? SORTHO : 2.f * SORTHO;
        float s, c;
        __sincosf((float)((k * t) & 511) * 0.01227184630f, &s, &c);
        v = (kidx & 1) ? -s * hw : c * hw;
      }
      if (h == 0) v0 = v; else v1 = v;
    }
    pk[jp] = f2bf(v0) | (f2bf(v1) << 16);
  }
  *(uint4*)(ITWf + slot * 8) = make_uint4(pk[0], pk[1], pk[2], pk[3]);
}

// ---------- K2: csd[b][k] = (1/(256*sqrt(512))) * DFT_t( autocorr(s)[t-255] )
// grid (2,128). Conflict-free autocorr + rotation-recurrence DFT (v4-proven).
__global__ __launch_bounds__(256) void k_csd(const float* __restrict__ x,
                                             float* __restrict__ csd) {
  __shared__ float sl[768];
  __shared__ float ac[257];
  __shared__ float red[4];
  const int tid = threadIdx.x, bh = blockIdx.x, bb = blockIdx.y;
  for (int t = tid; t < 768; t += 256) {
    float v = 0.f;
    if (t < 512) {
      const float4* xp = (const float4*)(x + (bb * 512 + t) * 16);
      float4 a = xp[0], b = xp[1], c = xp[2], d = xp[3];
      v = a.x + a.y + a.z + a.w + b.x + b.y + b.z + b.w +
          c.x + c.y + c.z + c.w + d.x + d.y + d.z + d.w;
    }
    sl[t] = v;
  }
  __syncthreads();
  {
    float a0 = 0.f, a1 = 0.f, a2 = 0.f, a3 = 0.f;
    for (int tau = 0; tau < 512; tau += 4) {
      float4 u = *(const float4*)&sl[tau];
      a0 = fmaf(u.x, sl[tau + tid], a0);
      a1 = fmaf(u.y, sl[tau + tid + 1], a1);
      a2 = fmaf(u.z, sl[tau + tid + 2], a2);
      a3 = fmaf(u.w, sl[tau + tid + 3], a3);
    }
    ac[tid] = (a0 + a1) + (a2 + a3);
  }
  {
    float p = sl[tid] * sl[tid + 256];
#pragma unroll
    for (int off = 32; off; off >>= 1) p += __shfl_down(p, off);
    if ((tid & 63) == 0) red[tid >> 6] = p;
  }
  __syncthreads();
  if (tid == 0) ac[256] = red[0] + red[1] + red[2] + red[3];
  __syncthreads();
  const float S1 = SORTHO / 256.f;
  const int k = bh * 129 + tid;
  const int kmax = (bh == 0) ? 129 : 128;
  if (tid < kmax) {
    float sth, cth;
    __sincosf((float)k * 0.01227184630f, &sth, &cth);
    float c = 1.f, s = 0.f, re = 0.f, im = 0.f;
    for (int t = 0; t < 512; ++t) {
      int d = t - 255;
      float ov = ac[d < 0 ? -d : d];
      re = fmaf(ov, c, re);
      im = fmaf(-ov, s, im);
      float nc = fmaf(c, cth, -s * sth);
      s = fmaf(s, cth, c * sth);
      c = nc;
    }
    *(float2*)(csd + (bb * NF_ + k) * 2) = make_float2(re * S1, im * S1);
  }
}

// ---------- K3: rfft GEMM: fftc = TWf x X^T + csd. grid (2,128) x 512 thr.
__global__ __launch_bounds__(512) void k_fftg(const float* __restrict__ x,
                                              const unsigned short* __restrict__ TWf,
                                              const float* __restrict__ csd,
                                              float* __restrict__ fftc) {
  __shared__ __align__(16) unsigned short Xs[16 * 512];
  const int tid = threadIdx.x, mh = blockIdx.x, bb = blockIdx.y;
#pragma unroll
  for (int it = 0; it < 16; ++it) {
    int e = it * 512 + tid;
    int f = e & 15, t = e >> 4;
    float val = x[(bb * 512 + t) * 16 + f];
    Xs[f * 512 + (((t >> 3) ^ (f & 7)) * 8) + (t & 7)] = (unsigned short)f2bf(val);
  }
  __syncthreads();
  const int lane = tid & 63, wave = tid >> 6;   // 8 waves
  const int l15 = lane & 15, quad = lane >> 4;
  floatx4 acc0 = {0,0,0,0}, acc1 = {0,0,0,0}, acc2 = {0,0,0,0};
  const int g0 = mh * 17 + wave, g1 = g0 + 8, g2 = mh * 17 + 16;
#pragma unroll
  for (int ks = 0; ks < 16; ++ks) {
    short8 bf = *(const short8*)&Xs[l15 * 512 + (((ks * 4 + quad) ^ (l15 & 7)) * 8)];
    short8 af0 = *(const short8*)(TWf + g0 * 8192 + ks * 512 + quad * 128 + l15 * 8);
    short8 af1 = *(const short8*)(TWf + g1 * 8192 + ks * 512 + quad * 128 + l15 * 8);
    acc0 = __builtin_amdgcn_mfma_f32_16x16x32_bf16(af0, bf, acc0, 0, 0, 0);
    acc1 = __builtin_amdgcn_mfma_f32_16x16x32_bf16(af1, bf, acc1, 0, 0, 0);
    if (wave == 0) {
      short8 af2 = *(const short8*)(TWf + g2 * 8192 + ks * 512 + quad * 128 + l15 * 8);
      acc2 = __builtin_amdgcn_mfma_f32_16x16x32_bf16(af2, bf, acc2, 0, 0, 0);
    }
  }
#pragma unroll
  for (int i = 0; i < 3; ++i) {
    if (i == 2 && wave != 0) break;
    const int g = (i == 0) ? g0 : (i == 1) ? g1 : g2;
    floatx4 a = (i == 0) ? acc0 : (i == 1) ? acc1 : acc2;
#pragma unroll
    for (int r = 0; r < 4; ++r) {
      const int grow = g * 16 + quad * 4 + r;
      if (grow < 514) {
        const int k = grow >> 1, ri = grow & 1;
        fftc[((bb * NF_ + k) * 16 + l15) * 2 + ri] =
            a[r] + csd[(bb * NF_ + k) * 2 + ri];
      }
    }
  }
}

// ---------- K4: new_fft[b][n][f] from recomputed proj + per-freq complexifier
__global__ __launch_bounds__(256) void k_new(const float* __restrict__ fftc,
                                             const float* __restrict__ W_proj,
                                             const float* __restrict__ b_proj,
                                             const float* __restrict__ mag_w,
                                             const float* __restrict__ mag_b,
                                             const float* __restrict__ phase_w,
                                             const float* __restrict__ phase_b,
                                             float* __restrict__ nf) {
  __shared__ float wp[256], bp[64];
  const int tid = threadIdx.x;
  wp[tid] = W_proj[tid];
  if (tid < 64) bp[tid] = b_proj[tid];
  __syncthreads();
  const int idx = blockIdx.x * 256 + tid;
  const int bn = idx >> 4;
  const int n = bn % NF_;
  float2 z = *(const float2*)(fftc + idx * 2);
  float d = z.x * z.x + z.y * z.y;
  float ir = d > 0.f ? rsqrtf(d) : 0.f;
  float mag = d * ir;
  float sn = z.y * ir;
  float cs = d > 0.f ? z.x * ir : 1.f;
  float fr = (float)n * 0.1953125f;  // 100/512
  float am = 0.f, ap = 0.f;
#pragma unroll 8
  for (int h = 0; h < 64; ++h) {
    float p = fmaf(mag, wp[h], fmaf(sn, wp[64 + h], fmaf(cs, wp[128 + h],
              fmaf(fr, wp[192 + h], bp[h]))));
    p = fmaxf(p, 0.f);
    am = fmaf(p, mag_w[n * 64 + h], am);
    ap = fmaf(p, phase_w[n * 64 + h], ap);
  }
  float m = fmaxf(am + mag_b[n], 0.f);
  float ph = 6.28318530718f / (1.f + __expf(-(ap + phase_b[n])));
  float sp, cp;
  __sincosf(ph, &sp, &cp);
  *(float2*)(nf + idx * 2) = make_float2(m * cp, m * sp);
}

// ---------- K5: gate GEMM. M=128, N=160 (nh), SPK=32 -> 1024 blocks, 3/CU.
__global__ __launch_bounds__(256, 3) void k_gemm(const float* __restrict__ fftc,
                                                 const float* __restrict__ W_proj,
                                                 const float* __restrict__ b_proj,
                                                 const unsigned short* __restrict__ wgt,
                                                 unsigned short* __restrict__ gpart) {
  __shared__ __align__(16) unsigned short As[128 * 64];
  __shared__ __align__(16) unsigned short Bs[160 * 64];
  __shared__ unsigned int zsp[128 * 9];
  const int tid = threadIdx.x;
  const int bid = blockIdx.x;
  const int xcd = bid & 7, jb = bid >> 3;     // jb in [0,128)
  const int mt = jb & 15;
  const int slice = xcd * 8 + (jb >> 4);      // [0,64)
  const int sp = slice >> 1, nh = slice & 1;
  const int i0 = (NF_ * sp) >> 5, i1 = (NF_ * (sp + 1)) >> 5;
  const int ni = i1 - i0;                     // 8 or 9

  const int r8 = tid >> 3, hg = tid & 7;
  float w0[8], w1[8], w2[8], w3[8], bpv[8];
#pragma unroll
  for (int jj = 0; jj < 8; ++jj) {
    int h = hg * 8 + jj;
    w0[jj] = W_proj[h];       w1[jj] = W_proj[64 + h];
    w2[jj] = W_proj[128 + h]; w3[jj] = W_proj[192 + h];
    bpv[jj] = b_proj[h];
  }
  const int nb2 = tid >> 3, kq = tid & 7;
  const unsigned short* bbase = wgt + (nh * 160 + nb2) * KDIM + kq * 8;

  const int lane = tid & 63, wave = tid >> 6;
  const int wm = wave & 1, wn = wave >> 1;
  const int l15 = lane & 15, quad = lane >> 4;

  floatx4 acc[4][5];
#pragma unroll
  for (int a = 0; a < 4; ++a)
#pragma unroll
    for (int b = 0; b < 5; ++b) acc[a][b] = (floatx4){0.f, 0.f, 0.f, 0.f};

  uint4 bv[5];
#pragma unroll
  for (int q = 0; q < 5; ++q)
    bv[q] = *(const uint4*)(bbase + q * (32 * KDIM) + i0 * 64);
  for (int li = tid; li < 128 * ni; li += 256) {
    int r = li & 127, ii = li >> 7;
    int gm = mt * 128 + r;
    float2 z = *(const float2*)(fftc + (((gm >> 4) * NF_ + i0 + ii) * 16 + (gm & 15)) * 2);
    zsp[r * 9 + ii] = f2bf(z.x) | (f2bf(z.y) << 16);
  }
  __syncthreads();

  for (int i = i0; i < i1; ++i) {
    const int ii = i - i0;
    const float fr = (float)i * 0.1953125f;
    unsigned int pk[4][4];
#pragma unroll
    for (int g = 0; g < 4; ++g) {
      unsigned int zp = zsp[(r8 + 32 * g) * 9 + ii];
      float zr = bf2f(zp & 0xFFFFu), zi = bf2f(zp >> 16);
      float d = zr * zr + zi * zi;
      float ir = d > 0.f ? rsqrtf(d) : 0.f;
      float mag = d * ir, sn = zi * ir, cs = d > 0.f ? zr * ir : 1.f;
#pragma unroll
      for (int jj = 0; jj < 4; ++jj) {
        float p0 = fmaf(mag, w0[2 * jj], fmaf(sn, w1[2 * jj],
                   fmaf(cs, w2[2 * jj], fmaf(fr, w3[2 * jj], bpv[2 * jj]))));
        float p1 = fmaf(mag, w0[2 * jj + 1], fmaf(sn, w1[2 * jj + 1],
                   fmaf(cs, w2[2 * jj + 1], fmaf(fr, w3[2 * jj + 1], bpv[2 * jj + 1]))));
        p0 = fmaxf(p0, 0.f); p1 = fmaxf(p1, 0.f);
        pk[g][jj] = f2bf(p0) | (f2bf(p1) << 16);
      }
    }
    __syncthreads();
#pragma unroll
    for (int g = 0; g < 4; ++g) {
      int row = r8 + 32 * g;
      *(uint4*)&As[row * 64 + ((hg ^ (row & 7)) * 8)] =
          make_uint4(pk[g][0], pk[g][1], pk[g][2], pk[g][3]);
    }
#pragma unroll
    for (int q = 0; q < 5; ++q) {
      int row = nb2 + 32 * q;
      *(uint4*)&Bs[row * 64 + ((kq ^ (row & 7)) * 8)] = bv[q];
    }
    __syncthreads();
    {
      const int ix = (i + 1 < i1) ? i + 1 : i;
#pragma unroll
      for (int q = 0; q < 5; ++q)
        bv[q] = *(const uint4*)(bbase + q * (32 * KDIM) + ix * 64);
    }
#pragma unroll
    for (int kh = 0; kh < 2; ++kh) {
      const int kqr = kh * 4 + quad;
      short8 af[4];
#pragma unroll
      for (int mi = 0; mi < 4; ++mi) {
        int row = wm * 64 + mi * 16 + l15;
        af[mi] = *(const short8*)&As[row * 64 + ((kqr ^ (row & 7)) * 8)];
      }
#pragma unroll
      for (int nn = 0; nn < 5; ++nn) {
        int row = wn * 80 + nn * 16 + l15;
        short8 bfv = *(const short8*)&Bs[row * 64 + ((kqr ^ (row & 7)) * 8)];
#pragma unroll
        for (int mi = 0; mi < 4; ++mi)
          acc[mi][nn] = __builtin_amdgcn_mfma_f32_16x16x32_bf16(af[mi], bfv,
                                                                acc[mi][nn], 0, 0, 0);
      }
    }
  }
  unsigned short* gp = gpart + (size_t)slice * (2048 * 160);
#pragma unroll
  for (int mi = 0; mi < 4; ++mi)
#pragma unroll
    for (int nn = 0; nn < 5; ++nn)
#pragma unroll
      for (int r = 0; r < 4; ++r) {
        int row = mt * 128 + wm * 64 + mi * 16 + quad * 4 + r;
        int col = wn * 80 + nn * 16 + l15;
        gp[row * 160 + col] = (unsigned short)f2bf(acc[mi][nn][r]);
      }
}

// ---------- K5r: sum split-K bf16 partials + bias -> SiLU -> sigmoid -> w
__global__ __launch_bounds__(256) void k_wred(const unsigned short* __restrict__ gpart,
                                              const float* __restrict__ b_gate,
                                              float* __restrict__ wbuf) {
  const int m = blockIdx.x;
  for (int n = threadIdx.x; n < NF_; n += 256) {
    const int half = (n >= 160) ? 1 : 0;
    const int col = n - half * 160;
    float g = b_gate[n];
#pragma unroll
    for (int s2 = 0; s2 < SPK; ++s2)
      g += bf2f((unsigned int)gpart[((size_t)(s2 * 2 + half) * 2048 + m) * 160 + col]);
    float sg = 1.f / (1.f + __expf(-g));
    float gs = g * sg;
    wbuf[m * NF_ + n] = 1.f / (1.f + __expf(-gs));
  }
}

// ---------- K6: irfft GEMM: out = LN(ITWf x WF^T + x). grid (2,128) x 512 thr.
__global__ __launch_bounds__(512) void k_recong(const float* __restrict__ fftc,
                                                const float* __restrict__ nfb,
                                                const float* __restrict__ wbuf,
                                                const unsigned short* __restrict__ ITWf,
                                                const float* __restrict__ x,
                                                const float* __restrict__ ln_g,
                                                const float* __restrict__ ln_b,
                                                float* __restrict__ out) {
  __shared__ __align__(16) unsigned short WFs[16 * 576];
  __shared__ float wls[16 * 257];
  const int tid = threadIdx.x, th = blockIdx.x, bb = blockIdx.y;
  // stage wbuf coalesced
  for (int e = tid; e < 4096; e += 512) {
    int f = e >> 8, n = e & 255;
    wls[f * 257 + n] = wbuf[(bb * 16 + f) * NF_ + n];
  }
  if (tid < 16) wls[tid * 257 + 256] = wbuf[(bb * 16 + tid) * NF_ + 256];
  __syncthreads();
#pragma unroll
  for (int it = 0; it < 17; ++it) {
    int e = it * 512 + tid;        // < 8704 = 16*544
    int f = e & 15, row = e >> 4;
    float val = 0.f;
    if (row < 514) {
      int k = row >> 1, ri = row & 1;
      int base = ((bb * NF_ + k) * 16 + f) * 2 + ri;
      float fz = fftc[base], nz = nfb[base];
      float wv = wls[f * 257 + k];
      val = fz + wv * (nz - fz);
    }
    WFs[f * 576 + (((row >> 3) ^ (f & 7)) * 8) + (row & 7)] = (unsigned short)f2bf(val);
  }
  __syncthreads();
  const int lane = tid & 63, wave = tid >> 6;   // 8 waves x 2 tiles
  const int l15 = lane & 15, quad = lane >> 4;
  const float gg = ln_g[l15], gb = ln_b[l15];
  floatx4 acc[2];
  acc[0] = (floatx4){0.f, 0.f, 0.f, 0.f};
  acc[1] = (floatx4){0.f, 0.f, 0.f, 0.f};
  const int tg0 = th * 16 + wave, tg1 = tg0 + 8;
#pragma unroll
  for (int ks = 0; ks < 17; ++ks) {
    short8 bf = *(const short8*)&WFs[l15 * 576 + (((ks * 4 + quad) ^ (l15 & 7)) * 8)];
    short8 af0 = *(const short8*)(ITWf + tg0 * 8704 + ks * 512 + quad * 128 + l15 * 8);
    short8 af1 = *(const short8*)(ITWf + tg1 * 8704 + ks * 512 + quad * 128 + l15 * 8);
    acc[0] = __builtin_amdgcn_mfma_f32_16x16x32_bf16(af0, bf, acc[0], 0, 0, 0);
    acc[1] = __builtin_amdgcn_mfma_f32_16x16x32_bf16(af1, bf, acc[1], 0, 0, 0);
  }
#pragma unroll
  for (int i = 0; i < 2; ++i) {
    const int tg = (i == 0) ? tg0 : tg1;
#pragma unroll
    for (int r = 0; r < 4; ++r) {
      const int t = tg * 16 + quad * 4 + r;
      float y = acc[i][r] + x[(bb * 512 + t) * 16 + l15];
      float s1 = y, s2 = y * y;
#pragma unroll
      for (int m = 1; m < 16; m <<= 1) {
        s1 += __shfl_xor(s1, m);
        s2 += __shfl_xor(s2, m);
      }
      float mu = s1 * 0.0625f;
      float var = s2 * 0.0625f - mu * mu;
      float rs = rsqrtf(var + 1e-5f);
      out[(bb * 512 + t) * 16 + l15] = (y - mu) * rs * gg + gb;
    }
  }
}

extern "C" void kernel_launch(void* const* d_in, const int* in_sizes, int n_in,
                              void* d_out, int out_size, void* d_ws, size_t ws_size,
                              hipStream_t stream) {
  const float* x = (const float*)d_in[0];
  const float* W_proj = (const float*)d_in[1];
  const float* b_proj = (const float*)d_in[2];
  const float* W_gate = (const float*)d_in[3];
  const float* b_gate = (const float*)d_in[4];
  const float* mag_w = (const float*)d_in[5];
  const float* mag_b = (const float*)d_in[6];
  const float* phase_w = (const float*)d_in[7];
  const float* phase_b = (const float*)d_in[8];
  const float* ln_g = (const float*)d_in[9];
  const float* ln_b = (const float*)d_in[10];
  float* out = (float*)d_out;
  float* ws = (float*)d_ws;

  // workspace (float slots), ~64.4 MB (ws = 256 MB per harness fill)
  float* fftc = ws;                                          // 1,052,672
  float* nfb = ws + 1052672;                                 // 1,052,672
  float* wbuf = ws + 2105344;                                //   526,336
  float* csd = ws + 2631680;                                 //    65,792
  unsigned short* gpart = (unsigned short*)(ws + 2697472);   // 64*2048*160 bf16
  unsigned short* wgt = (unsigned short*)(ws + 13183232);    // 320*16448 bf16
  unsigned short* TWf = (unsigned short*)(ws + 15814912);    // 278,528 sh
  unsigned short* ITWf = (unsigned short*)(ws + 15954176);   // 278,528 sh

  hipLaunchKernelGGL(k_wgt, dim3(257, 10), dim3(256), 0, stream, W_gate, wgt);
  hipLaunchKernelGGL(k_tw, dim3(136), dim3(256), 0, stream, TWf);
  hipLaunchKernelGGL(k_itw, dim3(136), dim3(256), 0, stream, ITWf);
  hipLaunchKernelGGL(k_csd, dim3(2, 128), dim3(256), 0, stream, x, csd);
  hipLaunchKernelGGL(k_fftg, dim3(2, 128), dim3(512), 0, stream, x, TWf, csd, fftc);
  hipLaunchKernelGGL(k_new, dim3(2056), dim3(256), 0, stream, fftc, W_proj, b_proj,
                     mag_w, mag_b, phase_w, phase_b, nfb);
  hipLaunchKernelGGL(k_gemm, dim3(1024), dim3(256), 0, stream, fftc, W_proj,
                     b_proj, wgt, gpart);
  hipLaunchKernelGGL(k_wred, dim3(2048), dim3(256), 0, stream, gpart, b_gate, wbuf);
  hipLaunchKernelGGL(k_recong, dim3(2, 128), dim3(512), 0, stream, fftc, nfb, wbuf,
                     ITWf, x, ln_g, ln_b, out);
}